// Round 4
// baseline (716.211 us; speedup 1.0000x reference)
//
#include <hip/hip_runtime.h>
#include <stdint.h>

// Problem constants
constexpr int B_ = 8, N_ = 4096, E_ = 2048, C_ = 128;
constexpr int CN = 144;   // 128 channels + 1 ones-col + 15 pad
constexpr int KT = 32;    // K per MFMA tile-step (== one 32-bit H word)
constexpr int MT = 64;    // M tile per block (4 waves x 16 rows)
constexpr int LROW = 40;  // padded LDS row (bf16 elems)
constexpr int HBW = 64;   // Hbits words per node row (2048/32)

typedef short bf16x8 __attribute__((ext_vector_type(8)));
typedef float f32x4  __attribute__((ext_vector_type(4)));

__device__ inline uint16_t bf16_rne(float f) {
    uint32_t u = __builtin_bit_cast(uint32_t, f);
    return (uint16_t)((u + 0x7FFFu + ((u >> 16) & 1u)) >> 16);
}

constexpr size_t HB_E  = (size_t)B_ * N_ * HBW;  // 2M u32 = 8 MB
constexpr size_t WT_E  = (size_t)CN * C_;        // bf16 W^T padded
constexpr size_t EBF_E = (size_t)B_ * CN * E_;   // ebfT bf16

// ---------------------------------------------------------------------------
// pack: H (fp32 0/1, 268 MB) -> Hbits[b][n][64] (bit j of word w = H[n][32w+j])
// One wave handles 256 e's per group via 4 ballots. HBM-bound.
// ---------------------------------------------------------------------------
__global__ void pack_kernel(const float* __restrict__ H, uint32_t* __restrict__ Hb) {
    const int lane = threadIdx.x & 63;
    const int wid  = (blockIdx.x * blockDim.x + threadIdx.x) >> 6;
    const int nw   = (gridDim.x * blockDim.x) >> 6;
    const int NG   = B_ * N_ * (E_ / 256);       // 262144 wave-groups
    for (int g = wid; g < NG; g += nw) {
        int row = g >> 3;                        // b*N + n
        int e0  = (g & 7) * 256;
        const float* hp = H + (size_t)row * E_ + e0 + lane;
        float v0 = hp[0], v1 = hp[64], v2 = hp[128], v3 = hp[192];
        uint64_t b0 = __ballot(v0 > 0.5f);
        uint64_t b1 = __ballot(v1 > 0.5f);
        uint64_t b2 = __ballot(v2 > 0.5f);
        uint64_t b3 = __ballot(v3 > 0.5f);
        if (lane == 0) {
            uint32_t* op = Hb + (size_t)row * HBW + (e0 >> 5);
            ((uint4*)op)[0] = make_uint4((uint32_t)b0, (uint32_t)(b0 >> 32),
                                         (uint32_t)b1, (uint32_t)(b1 >> 32));
            ((uint4*)op)[1] = make_uint4((uint32_t)b2, (uint32_t)(b2 >> 32),
                                         (uint32_t)b3, (uint32_t)(b3 >> 32));
        }
    }
}

// ---------------------------------------------------------------------------
// prep: WTb = bf16(W^T) padded to 144 rows; constant rows 128..143 of xwbT
// (in d_out) and ebfT (in ws): row 128 = 1.0 (ones-col -> s_e / d_n), rest 0.
// ---------------------------------------------------------------------------
__global__ void prep_kernel(const float* __restrict__ W, uint16_t* __restrict__ WTb,
                            uint32_t* __restrict__ xwbT32, uint32_t* __restrict__ ebfT32) {
    const int NW = (int)WT_E;                  // 18432
    const int NX = B_ * 16 * (N_ / 2);         // 262144 dwords
    const int NE = B_ * 16 * (E_ / 2);         // 131072 dwords
    int stride = gridDim.x * blockDim.x;
    for (int i = blockIdx.x * blockDim.x + threadIdx.x; i < NW + NX + NE; i += stride) {
        if (i < NW) {
            int c = i >> 7, k = i & 127;
            WTb[i] = bf16_rne((c < C_) ? W[k * C_ + c] : 0.f);
        } else if (i < NW + NX) {
            int j = i - NW;
            int b = j >> 15, rr = j & 32767;
            int r = rr >> 11, n2 = rr & 2047;
            xwbT32[((size_t)b * CN + (C_ + r)) * (N_ / 2) + n2] = (r == 0) ? 0x3F803F80u : 0u;
        } else {
            int j = i - NW - NX;
            int b = j >> 14, rr = j & 16383;
            int r = rr >> 10, e2 = rr & 1023;
            ebfT32[((size_t)b * CN + (C_ + r)) * (E_ / 2) + e2] = (r == 0) ? 0x3F803F80u : 0u;
        }
    }
}

// ---------------------------------------------------------------------------
// MFMA GEMM. No split-K, no atomics, no partials.
//  MODE 0 (fc) : A = x [4096x128] fp32 NT,  B = WTb,  out: bf16 C^T xwbT (+bias)
//  MODE 1 (v2e): A = H^T bits (Hbits),      B = xwbT, out: bf16 C^T ebfT (x 1/s_e)
//  MODE 2 (e2v): A = H bits (Hbits),        B = ebfT, out: fp32 row-major (x 1/d_n)
// 256 thr = 4 waves, M-tile 64, 9 col tiles (col 128 = ones-col count).
// Register pipeline: A 2 iters ahead, B 1 iter ahead.
// ---------------------------------------------------------------------------
template <int MODE>
__global__ __launch_bounds__(256, 3)
void gemm_k(const float* __restrict__ Ax, const uint32_t* __restrict__ Hb,
            const uint16_t* __restrict__ Btb, const float* __restrict__ bias,
            uint16_t* __restrict__ outT, float* __restrict__ outF) {
    constexpr int  K   = (MODE == 0) ? C_ : (MODE == 1) ? N_ : E_;
    constexpr int  M   = (MODE == 1) ? E_ : N_;
    constexpr int  S   = K / KT;                  // 4 / 128 / 64 (all even)
    constexpr int  NMT = M / MT;
    constexpr int  LDB = K;
    constexpr size_t BBS = (MODE == 0) ? 0 : (size_t)CN * K;
    constexpr int  OLD = (MODE == 0) ? N_ : E_;   // modes 0/1 transposed-out ld
    constexpr int  NSEG = CN * KT / 8;            // 576 16B segments of B tile

    __shared__ uint16_t Alds[MT * LROW];
    __shared__ uint16_t Blds[CN * LROW];
    __shared__ float    s_sh[MT];

    const int t     = threadIdx.x;
    const int batch = blockIdx.x & 7;             // XCD spread; per-batch panels stay in L2
    const int mtile = blockIdx.x >> 3;
    const int m0    = (mtile % NMT) * MT;
    const int lane  = t & 63, wave = t >> 6;
    const int l15   = lane & 15, quad = lane >> 4;

    const uint16_t* Bp  = Btb + (size_t)batch * BBS;
    const float*    ApF = (MODE == 0) ? Ax + (size_t)batch * N_ * C_ : nullptr;
    const uint32_t* ApB = (MODE == 0) ? nullptr : Hb + (size_t)batch * N_ * HBW;

    f32x4 acc[9];
#pragma unroll
    for (int j = 0; j < 9; ++j) acc[j] = (f32x4){0.f, 0.f, 0.f, 0.f};

    // A-load thread mapping
    int am, ak;
    if (MODE == 0) { am = t >> 2; ak = (t & 3) * 8; }
    else           { am = t & 63; ak = (t >> 6) * 8; }

    float    afv[2][8];   // MODE 0 prefetch
    uint32_t awv[2][8];   // MODE 1: 8 words (one per k=n), bit = e&31
    uint32_t aw2[2];      // MODE 2: 1 word (row n=am, bits = e-offsets)
    uint4    bvv[2][3];

    auto loadA = [&](int k0, int slot) {
        if constexpr (MODE == 0) {
            const float* ap = ApF + (size_t)(m0 + am) * C_ + (k0 + ak);
            const float4 f0 = *(const float4*)ap;
            const float4 f1 = *(const float4*)(ap + 4);
            afv[slot][0] = f0.x; afv[slot][1] = f0.y; afv[slot][2] = f0.z; afv[slot][3] = f0.w;
            afv[slot][4] = f1.x; afv[slot][5] = f1.y; afv[slot][6] = f1.z; afv[slot][7] = f1.w;
        } else if constexpr (MODE == 1) {
            // word for (n = k0+ak+i, e = m0+am): row n, word (m0+am)>>5
            const uint32_t* ap = ApB + (size_t)(k0 + ak) * HBW + ((m0 + am) >> 5);
#pragma unroll
            for (int i = 0; i < 8; ++i) awv[slot][i] = ap[(size_t)i * HBW];
        } else {
            aw2[slot] = ApB[(size_t)(m0 + am) * HBW + (k0 >> 5)];
        }
    };
    auto loadB = [&](int k0, int slot) {
#pragma unroll
        for (int jj = 0; jj < 3; ++jj) {
            int seg = t + 256 * jj;
            if (seg < NSEG) {
                int c = seg >> 2, kk = (seg & 3) * 8;
                bvv[slot][jj] = *(const uint4*)(Bp + (size_t)c * LDB + k0 + kk);
            }
        }
    };

    auto do_iter = [&](int s, int slot) {
        __syncthreads();                          // prev iter fragment reads done
        uint32_t p[4];
        if constexpr (MODE == 0) {
#pragma unroll
            for (int ii = 0; ii < 4; ++ii)
                p[ii] = (uint32_t)bf16_rne(afv[slot][2 * ii]) |
                        ((uint32_t)bf16_rne(afv[slot][2 * ii + 1]) << 16);
        } else if constexpr (MODE == 1) {
            const int bit = am & 31;
#pragma unroll
            for (int ii = 0; ii < 4; ++ii)
                p[ii] = (((awv[slot][2 * ii] >> bit) & 1u) ? 0x3F80u : 0u) |
                        (((awv[slot][2 * ii + 1] >> bit) & 1u) ? 0x3F800000u : 0u);
        } else {
            const uint32_t w = aw2[slot];
#pragma unroll
            for (int ii = 0; ii < 4; ++ii)
                p[ii] = (((w >> (ak + 2 * ii)) & 1u) ? 0x3F80u : 0u) |
                        (((w >> (ak + 2 * ii + 1)) & 1u) ? 0x3F800000u : 0u);
        }
        *(uint4*)&Alds[am * LROW + ak] = make_uint4(p[0], p[1], p[2], p[3]);
#pragma unroll
        for (int jj = 0; jj < 3; ++jj) {
            int seg = t + 256 * jj;
            if (seg < NSEG) *(uint4*)&Blds[(seg >> 2) * LROW + (seg & 3) * 8] = bvv[slot][jj];
        }
        if (s + 2 < S) loadA((s + 2) * KT, slot);           // regs free after LDS store
        if (s + 1 < S) loadB((s + 1) * KT, slot ^ 1);
        __syncthreads();
        bf16x8 af = *(const bf16x8*)&Alds[(wave * 16 + l15) * LROW + quad * 8];
#pragma unroll
        for (int j = 0; j < 9; ++j) {
            bf16x8 bf = *(const bf16x8*)&Blds[(j * 16 + l15) * LROW + quad * 8];
            acc[j] = __builtin_amdgcn_mfma_f32_16x16x32_bf16(af, bf, acc[j], 0, 0, 0);
        }
    };

    loadA(0, 0);
    if (S > 1) loadA(KT, 1);
    loadB(0, 0);
#pragma unroll 1
    for (int s = 0; s < S; s += 2) {
        do_iter(s, 0);
        do_iter(s + 1, 1);
    }

    // ---- epilogue ----
    const int row = m0 + wave * 16 + quad * 4;
    if constexpr (MODE == 0) {
#pragma unroll
        for (int j = 0; j < 8; ++j) {
            int c = j * 16 + l15;
            float add = bias[c];
            uint32_t q0 = (uint32_t)bf16_rne(acc[j][0] + add) | ((uint32_t)bf16_rne(acc[j][1] + add) << 16);
            uint32_t q1 = (uint32_t)bf16_rne(acc[j][2] + add) | ((uint32_t)bf16_rne(acc[j][3] + add) << 16);
            uint16_t* op = outT + ((size_t)batch * CN + c) * OLD + row;
            *(uint2*)op = make_uint2(q0, q1);
        }
    } else {
        // broadcast ones-col counts (s_e / d_n) to all lanes of each quad
        if (l15 == 0) {
#pragma unroll
            for (int r = 0; r < 4; ++r) s_sh[wave * 16 + quad * 4 + r] = acc[8][r];
        }
        __syncthreads();
        float mul[4];
#pragma unroll
        for (int r = 0; r < 4; ++r) {
            float sv = s_sh[wave * 16 + quad * 4 + r];
            mul[r] = (sv > 0.f) ? 1.f / sv : 0.f;
        }
        if constexpr (MODE == 1) {
#pragma unroll
            for (int j = 0; j < 8; ++j) {
                int c = j * 16 + l15;
                uint32_t q0 = (uint32_t)bf16_rne(acc[j][0] * mul[0]) |
                              ((uint32_t)bf16_rne(acc[j][1] * mul[1]) << 16);
                uint32_t q1 = (uint32_t)bf16_rne(acc[j][2] * mul[2]) |
                              ((uint32_t)bf16_rne(acc[j][3] * mul[3]) << 16);
                uint16_t* op = outT + ((size_t)batch * CN + c) * OLD + row;
                *(uint2*)op = make_uint2(q0, q1);
            }
        } else {
            float* op = outF + ((size_t)batch * N_ + row) * C_;
#pragma unroll
            for (int j = 0; j < 8; ++j) {
                int c = j * 16 + l15;
#pragma unroll
                for (int r = 0; r < 4; ++r) op[(size_t)r * C_ + c] = acc[j][r] * mul[r];
            }
        }
    }
}

// ---------------------------------------------------------------------------
extern "C" void kernel_launch(void* const* d_in, const int* in_sizes, int n_in,
                              void* d_out, int out_size, void* d_ws, size_t ws_size,
                              hipStream_t stream) {
    const float* x    = (const float*)d_in[0];   // [8,4096,128]
    const float* H    = (const float*)d_in[1];   // [8,4096,2048]
    const float* W    = (const float*)d_in[2];   // [128,128]
    const float* bias = (const float*)d_in[3];   // [128]
    float* out = (float*)d_out;                  // [8,4096,128]

    // ws layout (~12.5 MB): Hbits (8 MB) | WTb (36 KB) | ebfT (4.7 MB)
    uint32_t* Hb   = (uint32_t*)d_ws;
    uint16_t* WTb  = (uint16_t*)(Hb + HB_E);
    uint16_t* ebfT = WTb + WT_E;
    uint16_t* xwbT = (uint16_t*)d_out;           // 9.4 MB scratch in d_out, dead before e2v

    pack_kernel<<<dim3(2048), dim3(256), 0, stream>>>(H, Hb);
    prep_kernel<<<dim3(1024), dim3(256), 0, stream>>>(W, WTb, (uint32_t*)xwbT, (uint32_t*)ebfT);
    gemm_k<0><<<dim3(8 * (N_ / MT)), dim3(256), 0, stream>>>(x, nullptr, WTb, bias, xwbT, nullptr);
    gemm_k<1><<<dim3(8 * (E_ / MT)), dim3(256), 0, stream>>>(nullptr, Hb, xwbT, nullptr, ebfT, nullptr);
    gemm_k<2><<<dim3(8 * (N_ / MT)), dim3(256), 0, stream>>>(nullptr, Hb, ebfT, nullptr, nullptr, out);
}